// Round 1
// baseline (510.681 us; speedup 1.0000x reference)
//
#include <hip/hip_runtime.h>

// MultiHeadAttention MI355X (gfx950)
// B=2, S=2048, H=2048, NH=16, HD=128. fp32 in/out, bf16 MFMA compute.
// Pipeline: cast -> 3x proj GEMM (V transposed out) -> flash attention -> out GEMM.

typedef __bf16 bf16_t;
typedef __bf16 bf16x8 __attribute__((ext_vector_type(8)));
typedef float  f32x4  __attribute__((ext_vector_type(4)));

#define DEVI __device__ __forceinline__

DEVI void async_copy16(const void* gsrc, void* ldst) {
  __builtin_amdgcn_global_load_lds(
      (const __attribute__((address_space(1))) unsigned int*)gsrc,
      (__attribute__((address_space(3))) unsigned int*)ldst, 16, 0, 0);
}

constexpr int Bc = 2, Sc = 2048, Hc = 2048, NHc = 16, HDc = 128;
constexpr float SCALE_F = 0.088388347648318447f;  // 1/sqrt(128)

// ---------------------------------------------------------------- cast
__global__ void cast_f32_to_bf16(const float* __restrict__ in,
                                 bf16_t* __restrict__ out, int n) {
  int i = (blockIdx.x * 256 + threadIdx.x) * 8;
  if (i >= n) return;
  float4 f0 = *(const float4*)(in + i);
  float4 f1 = *(const float4*)(in + i + 4);
  union { bf16_t h[8]; uint4 u; } o;
  o.h[0] = (bf16_t)f0.x; o.h[1] = (bf16_t)f0.y;
  o.h[2] = (bf16_t)f0.z; o.h[3] = (bf16_t)f0.w;
  o.h[4] = (bf16_t)f1.x; o.h[5] = (bf16_t)f1.y;
  o.h[6] = (bf16_t)f1.z; o.h[7] = (bf16_t)f1.w;
  *(uint4*)(out + i) = o.u;
}

// ---------------------------------------------------------------- bt-GEMM
// C[m,n] = sum_k A[m,k]*Bw[n,k] + bias[n].  A: MxK bf16 rm, Bw: NxK bf16 rm.
// OUT_MODE 0: bf16 row-major MxN. 1: bf16 transposed to (B,NH,HD,S). 2: f32 MxN.
// BK=64 (128B rows), XOR-8 chunk swizzle: stored chunk c' = c ^ (row&7)
// -> both global_load_lds staging (contiguous) and ds_read_b128 frags (2-way) happy.
template <int M, int N, int K, int OUT_MODE>
__global__ __launch_bounds__(256, 2) void gemm_bt(const bf16_t* __restrict__ A,
                                                  const bf16_t* __restrict__ Bw,
                                                  const float* __restrict__ bias,
                                                  void* __restrict__ Cout) {
  constexpr int BM = 128, BN = 128, BK = 64;
  __shared__ __align__(16) bf16_t As[BM * BK];
  __shared__ __align__(16) bf16_t Bs[BN * BK];
  const int tid = threadIdx.x;
  const int lane = tid & 63;
  const int wave = tid >> 6;
  const int bm = blockIdx.x & (M / BM - 1);   // fastest: 32 blocks share one weight tile
  const int bn = blockIdx.x / (M / BM);
  const int wm = wave >> 1, wn = wave & 1;
  const int quad = lane >> 4, l15 = lane & 15;

  // staging: tile = 16 segments x 1024B; wave w owns segs [4w,4w+4)
  int s_r[4], s_c[4];
#pragma unroll
  for (int i = 0; i < 4; ++i) {
    int seg = wave * 4 + i;
    int r = seg * 8 + (lane >> 3);
    s_r[i] = r;
    s_c[i] = (lane & 7) ^ (r & 7);
  }
  const bf16_t* Abase = A + (size_t)bm * BM * K;
  const bf16_t* Bbase = Bw + (size_t)bn * BN * K;

  f32x4 zero4 = {0.f, 0.f, 0.f, 0.f};
  f32x4 acc[4][4];
#pragma unroll
  for (int i = 0; i < 4; ++i)
#pragma unroll
    for (int j = 0; j < 4; ++j) acc[i][j] = zero4;

  int arow[4], brow[4];
#pragma unroll
  for (int t = 0; t < 4; ++t) {
    arow[t] = wm * 64 + t * 16 + l15;
    brow[t] = wn * 64 + t * 16 + l15;
  }

  for (int kt = 0; kt < K / BK; ++kt) {
    const int k0 = kt * BK;
#pragma unroll
    for (int i = 0; i < 4; ++i) {
      int seg = wave * 4 + i;
      async_copy16(Abase + (size_t)s_r[i] * K + k0 + s_c[i] * 8, As + seg * 512);
      async_copy16(Bbase + (size_t)s_r[i] * K + k0 + s_c[i] * 8, Bs + seg * 512);
    }
    __syncthreads();
#pragma unroll
    for (int ks = 0; ks < 2; ++ks) {
      bf16x8 af[4], bfv[4];
#pragma unroll
      for (int mt = 0; mt < 4; ++mt)
        af[mt] = *(const bf16x8*)(As + arow[mt] * 64 +
                                  (((ks * 4 + quad) ^ (arow[mt] & 7)) * 8));
#pragma unroll
      for (int nt = 0; nt < 4; ++nt)
        bfv[nt] = *(const bf16x8*)(Bs + brow[nt] * 64 +
                                   (((ks * 4 + quad) ^ (brow[nt] & 7)) * 8));
#pragma unroll
      for (int mt = 0; mt < 4; ++mt)
#pragma unroll
        for (int nt = 0; nt < 4; ++nt)
          acc[mt][nt] = __builtin_amdgcn_mfma_f32_16x16x32_bf16(
              af[mt], bfv[nt], acc[mt][nt], 0, 0, 0);
    }
    __syncthreads();
  }

  float bv[4];
#pragma unroll
  for (int nt = 0; nt < 4; ++nt) bv[nt] = bias[bn * BN + brow[nt]];

#pragma unroll
  for (int mt = 0; mt < 4; ++mt) {
    const int rbase = bm * BM + wm * 64 + mt * 16 + quad * 4;  // +r
#pragma unroll
    for (int nt = 0; nt < 4; ++nt) {
      const int col = bn * BN + brow[nt];
      if constexpr (OUT_MODE == 0) {
        bf16_t* C = (bf16_t*)Cout;
#pragma unroll
        for (int r = 0; r < 4; ++r)
          C[(size_t)(rbase + r) * N + col] = (bf16_t)(acc[mt][nt][r] + bv[nt]);
      } else if constexpr (OUT_MODE == 2) {
        float* C = (float*)Cout;
#pragma unroll
        for (int r = 0; r < 4; ++r)
          C[(size_t)(rbase + r) * N + col] = acc[mt][nt][r] + bv[nt];
      } else {  // transposed bf16 -> (B, NH, HD, S); 4 regs = 4 consecutive s
        bf16_t* C = (bf16_t*)Cout;
        const int bb = rbase >> 11;       // / S
        const int s0 = rbase & (Sc - 1);
        const int h = col >> 7, d = col & (HDc - 1);
        union { bf16_t h4[4]; uint2 u; } o;
#pragma unroll
        for (int r = 0; r < 4; ++r) o.h4[r] = (bf16_t)(acc[mt][nt][r] + bv[nt]);
        *(uint2*)(C + (((size_t)(bb * NHc + h) * HDc + d) * Sc + s0)) = o.u;
      }
    }
  }
}

// ---------------------------------------------------------------- flash attention
// grid = B*NH*(S/128); block = 256 (4 waves). Wave w owns q-rows [32w,32w+32).
// LDS: K tile 32KB | Vt tile 32KB | P (fp32, stride 132 floats) 66KB = 130KB dynamic.
__global__ __launch_bounds__(256, 1) void flash_attn(const bf16_t* __restrict__ Q,
                                                     const bf16_t* __restrict__ Kg,
                                                     const bf16_t* __restrict__ Vt,
                                                     bf16_t* __restrict__ ctx) {
  extern __shared__ char smem[];
  bf16_t* Ks = (bf16_t*)smem;              // 128 keys x 128 hd
  bf16_t* Vs = (bf16_t*)(smem + 32768);    // 128 hd x 128 keys (transposed V)
  float* Ps = (float*)(smem + 65536);      // per-wave 32 x 132 fp32

  const int tid = threadIdx.x, lane = tid & 63, wave = tid >> 6;
  const int quad = lane >> 4, l15 = lane & 15;
  const int bid = blockIdx.x;
  const int qt = bid & 15, h = (bid >> 4) & 15, b = bid >> 8;

  float* Pw = Ps + wave * (32 * 132);

  // Q fragments, held in registers for all 16 kv-tiles (softmax scale folded into exp)
  bf16x8 qf[2][4];
#pragma unroll
  for (int mt = 0; mt < 2; ++mt) {
    int grow = b * Sc + qt * 128 + wave * 32 + mt * 16 + l15;
    const bf16_t* qp = Q + (size_t)grow * Hc + h * HDc;
#pragma unroll
    for (int kc = 0; kc < 4; ++kc) qf[mt][kc] = *(const bf16x8*)(qp + kc * 32 + quad * 8);
  }

  f32x4 zero4 = {0.f, 0.f, 0.f, 0.f};
  f32x4 o[2][8];
#pragma unroll
  for (int mt = 0; mt < 2; ++mt)
#pragma unroll
    for (int dt = 0; dt < 8; ++dt) o[mt][dt] = zero4;
  float mrow[2][4], lrow[2][4];
#pragma unroll
  for (int mt = 0; mt < 2; ++mt)
#pragma unroll
    for (int r = 0; r < 4; ++r) { mrow[mt][r] = -1e30f; lrow[mt][r] = 0.f; }

  // staging geometry (K tile: 32 segs of 1024B = 4 rows x 256B; wave owns 8 segs)
  int st_r[8], st_c[8];
#pragma unroll
  for (int i = 0; i < 8; ++i) {
    int seg = wave * 8 + i;
    st_r[i] = seg * 4 + (lane >> 4);
    st_c[i] = (lane & 15) ^ (st_r[i] & 7);
  }
  const bf16_t* Kbase = Kg + (size_t)b * Sc * Hc + h * HDc;
  const bf16_t* Vbase = Vt + (size_t)(b * NHc + h) * HDc * Sc;

  for (int kb = 0; kb < 16; ++kb) {
#pragma unroll
    for (int i = 0; i < 8; ++i) {
      int seg = wave * 8 + i;
      async_copy16(Kbase + (size_t)(kb * 128 + st_r[i]) * Hc + st_c[i] * 8, Ks + seg * 512);
      async_copy16(Vbase + (size_t)st_r[i] * Sc + kb * 128 + st_c[i] * 8, Vs + seg * 512);
    }
    __syncthreads();

    // S = Q K^T  (kc outer -> 16 independent MFMA chains)
    f32x4 sf[2][8];
#pragma unroll
    for (int mt = 0; mt < 2; ++mt)
#pragma unroll
      for (int nt = 0; nt < 8; ++nt) sf[mt][nt] = zero4;
#pragma unroll
    for (int kc = 0; kc < 4; ++kc)
#pragma unroll
      for (int nt = 0; nt < 8; ++nt) {
        int kr = nt * 16 + l15;
        bf16x8 kf = *(const bf16x8*)(Ks + kr * 128 + (((kc * 4 + quad) ^ (kr & 7)) * 8));
        sf[0][nt] = __builtin_amdgcn_mfma_f32_16x16x32_bf16(qf[0][kc], kf, sf[0][nt], 0, 0, 0);
        sf[1][nt] = __builtin_amdgcn_mfma_f32_16x16x32_bf16(qf[1][kc], kf, sf[1][nt], 0, 0, 0);
      }

    // online softmax (raw-score max; scale folded into exp args)
#pragma unroll
    for (int mt = 0; mt < 2; ++mt)
#pragma unroll
      for (int r = 0; r < 4; ++r) {
        float mx = sf[mt][0][r];
#pragma unroll
        for (int nt = 1; nt < 8; ++nt) mx = fmaxf(mx, sf[mt][nt][r]);
#pragma unroll
        for (int off = 1; off < 16; off <<= 1) mx = fmaxf(mx, __shfl_xor(mx, off));
        float mnew = fmaxf(mrow[mt][r], mx);
        float alpha = __expf((mrow[mt][r] - mnew) * SCALE_F);
        float msc = mnew * SCALE_F;
        float rs = 0.f;
#pragma unroll
        for (int nt = 0; nt < 8; ++nt) {
          float p = __expf(sf[mt][nt][r] * SCALE_F - msc);
          sf[mt][nt][r] = p;
          rs += p;
        }
#pragma unroll
        for (int off = 1; off < 16; off <<= 1) rs += __shfl_xor(rs, off);
        lrow[mt][r] = lrow[mt][r] * alpha + rs;
        mrow[mt][r] = mnew;
#pragma unroll
        for (int dt = 0; dt < 8; ++dt) o[mt][dt][r] *= alpha;
      }

    // P: C-layout regs -> LDS (fp32, padded stride) -> A-layout bf16 frags (per-wave, no barrier)
#pragma unroll
    for (int mt = 0; mt < 2; ++mt)
#pragma unroll
      for (int nt = 0; nt < 8; ++nt)
#pragma unroll
        for (int r = 0; r < 4; ++r)
          Pw[(mt * 16 + quad * 4 + r) * 132 + nt * 16 + l15] = sf[mt][nt][r];

    bf16x8 pf[2][4];
#pragma unroll
    for (int mt = 0; mt < 2; ++mt) {
      const float* pr = Pw + (mt * 16 + l15) * 132;
#pragma unroll
      for (int kc = 0; kc < 4; ++kc) {
        f32x4 x0 = *(const f32x4*)(pr + kc * 32 + quad * 8);
        f32x4 x1 = *(const f32x4*)(pr + kc * 32 + quad * 8 + 4);
        bf16x8 t;
        t[0] = (bf16_t)x0[0]; t[1] = (bf16_t)x0[1]; t[2] = (bf16_t)x0[2]; t[3] = (bf16_t)x0[3];
        t[4] = (bf16_t)x1[0]; t[5] = (bf16_t)x1[1]; t[6] = (bf16_t)x1[2]; t[7] = (bf16_t)x1[3];
        pf[mt][kc] = t;
      }
    }

    // O += P V
#pragma unroll
    for (int kc = 0; kc < 4; ++kc)
#pragma unroll
      for (int dt = 0; dt < 8; ++dt) {
        int vr = dt * 16 + l15;
        bf16x8 vf = *(const bf16x8*)(Vs + vr * 128 + (((kc * 4 + quad) ^ (vr & 7)) * 8));
        o[0][dt] = __builtin_amdgcn_mfma_f32_16x16x32_bf16(pf[0][kc], vf, o[0][dt], 0, 0, 0);
        o[1][dt] = __builtin_amdgcn_mfma_f32_16x16x32_bf16(pf[1][kc], vf, o[1][dt], 0, 0, 0);
      }
    __syncthreads();
  }

  // epilogue: O/l -> LDS (reuse Pw) -> coalesced bf16 stores
#pragma unroll
  for (int mt = 0; mt < 2; ++mt) {
    float rinv[4];
#pragma unroll
    for (int r = 0; r < 4; ++r) rinv[r] = 1.f / lrow[mt][r];
#pragma unroll
    for (int dt = 0; dt < 8; ++dt)
#pragma unroll
      for (int r = 0; r < 4; ++r)
        Pw[(mt * 16 + quad * 4 + r) * 132 + dt * 16 + l15] = o[mt][dt][r] * rinv[r];
  }
#pragma unroll
  for (int r = 0; r < 32; ++r) {
    float2 v = *(const float2*)(Pw + r * 132 + lane * 2);
    union { bf16_t h[2]; unsigned u; } pk;
    pk.h[0] = (bf16_t)v.x; pk.h[1] = (bf16_t)v.y;
    int grow = b * Sc + qt * 128 + wave * 32 + r;
    *(unsigned*)(ctx + (size_t)grow * Hc + h * HDc + lane * 2) = pk.u;
  }
}

// ---------------------------------------------------------------- launch
extern "C" void kernel_launch(void* const* d_in, const int* in_sizes, int n_in,
                              void* d_out, int out_size, void* d_ws, size_t ws_size,
                              hipStream_t stream) {
  const float* query = (const float*)d_in[0];
  const float* key_i = (const float*)d_in[1];
  const float* value = (const float*)d_in[2];
  const float* Wq = (const float*)d_in[3];
  const float* bq = (const float*)d_in[4];
  const float* Wk = (const float*)d_in[5];
  const float* bk = (const float*)d_in[6];
  const float* Wv = (const float*)d_in[7];
  const float* bv = (const float*)d_in[8];
  const float* Wo = (const float*)d_in[9];
  const float* bo = (const float*)d_in[10];

  const size_t XE = (size_t)Bc * Sc * Hc;  // 8,388,608
  const size_t WE = (size_t)Hc * Hc;       // 4,194,304
  const size_t need = 6 * XE * 2 + 4 * WE * 2;  // 128 MB
  if (ws_size < need) return;

  char* ws = (char*)d_ws;
  size_t off = 0;
  auto alloc = [&](size_t bytes) {
    char* p = ws + off;
    off += (bytes + 255) & ~(size_t)255;
    return p;
  };
  bf16_t* Xq = (bf16_t*)alloc(XE * 2);
  bf16_t* Xk = (bf16_t*)alloc(XE * 2);
  bf16_t* Xv = (bf16_t*)alloc(XE * 2);
  bf16_t* Wqb = (bf16_t*)alloc(WE * 2);
  bf16_t* Wkb = (bf16_t*)alloc(WE * 2);
  bf16_t* Wvb = (bf16_t*)alloc(WE * 2);
  bf16_t* Wob = (bf16_t*)alloc(WE * 2);
  bf16_t* qb = (bf16_t*)alloc(XE * 2);
  bf16_t* kb = (bf16_t*)alloc(XE * 2);
  bf16_t* vtb = (bf16_t*)alloc(XE * 2);
  bf16_t* ctxb = Xq;  // Xq dead after q-projection; reuse for ctx

  cast_f32_to_bf16<<<(int)(XE / 2048), 256, 0, stream>>>(query, Xq, (int)XE);
  cast_f32_to_bf16<<<(int)(XE / 2048), 256, 0, stream>>>(key_i, Xk, (int)XE);
  cast_f32_to_bf16<<<(int)(XE / 2048), 256, 0, stream>>>(value, Xv, (int)XE);
  cast_f32_to_bf16<<<(int)(WE / 2048), 256, 0, stream>>>(Wq, Wqb, (int)WE);
  cast_f32_to_bf16<<<(int)(WE / 2048), 256, 0, stream>>>(Wk, Wkb, (int)WE);
  cast_f32_to_bf16<<<(int)(WE / 2048), 256, 0, stream>>>(Wv, Wvb, (int)WE);
  cast_f32_to_bf16<<<(int)(WE / 2048), 256, 0, stream>>>(Wo, Wob, (int)WE);

  gemm_bt<4096, 2048, 2048, 0><<<512, 256, 0, stream>>>(Xq, Wqb, bq, qb);
  gemm_bt<4096, 2048, 2048, 0><<<512, 256, 0, stream>>>(Xk, Wkb, bk, kb);
  gemm_bt<4096, 2048, 2048, 1><<<512, 256, 0, stream>>>(Xv, Wvb, bv, vtb);

  hipFuncSetAttribute((const void*)flash_attn,
                      hipFuncAttributeMaxDynamicSharedMemorySize, 133120);
  flash_attn<<<512, 256, 133120, stream>>>(qb, kb, vtb, ctxb);

  gemm_bt<4096, 2048, 2048, 2><<<512, 256, 0, stream>>>(ctxb, Wob, bo, (float*)d_out);
}

// Round 4
// 502.260 us; speedup vs baseline: 1.0168x; 1.0168x over previous
//
#include <hip/hip_runtime.h>

// MultiHeadAttention MI355X (gfx950)
// B=2, S=2048, H=2048, NH=16, HD=128. fp32 in/out, bf16 MFMA compute.
// Pipeline: cast -> 3x proj GEMM (V transposed out, Q pre-scaled) -> flash attention -> out GEMM.
// This round: round-1 flash geometry (4 waves, grid 512) + merged casts + scale folding + bf16 P.

typedef __bf16 bf16_t;
typedef __bf16 bf16x8 __attribute__((ext_vector_type(8)));
typedef float  f32x4  __attribute__((ext_vector_type(4)));

#define DEVI __device__ __forceinline__

DEVI void async_copy16(const void* gsrc, void* ldst) {
  __builtin_amdgcn_global_load_lds(
      (const __attribute__((address_space(1))) unsigned int*)gsrc,
      (__attribute__((address_space(3))) unsigned int*)ldst, 16, 0, 0);
}

constexpr int Bc = 2, Sc = 2048, Hc = 2048, NHc = 16, HDc = 128;
constexpr float SCALE_F = 0.088388347648318447f;  // 1/sqrt(128)
constexpr int PSTR = 136;  // bf16 elems; 136*2=272B=17*16 -> every row 16B-aligned

// ---------------------------------------------------------------- casts (merged launches)
DEVI void cast_body(const float* __restrict__ in, bf16_t* __restrict__ out) {
  int i = (blockIdx.x * 256 + threadIdx.x) * 8;
  float4 f0 = *(const float4*)(in + i);
  float4 f1 = *(const float4*)(in + i + 4);
  union { bf16_t h[8]; uint4 u; } o;
  o.h[0] = (bf16_t)f0.x; o.h[1] = (bf16_t)f0.y;
  o.h[2] = (bf16_t)f0.z; o.h[3] = (bf16_t)f0.w;
  o.h[4] = (bf16_t)f1.x; o.h[5] = (bf16_t)f1.y;
  o.h[6] = (bf16_t)f1.z; o.h[7] = (bf16_t)f1.w;
  *(uint4*)(out + i) = o.u;
}

__global__ void cast3(const float* __restrict__ a, const float* __restrict__ b,
                      const float* __restrict__ c, bf16_t* __restrict__ oa,
                      bf16_t* __restrict__ ob, bf16_t* __restrict__ oc) {
  const float* src = blockIdx.y == 0 ? a : blockIdx.y == 1 ? b : c;
  bf16_t* dst = blockIdx.y == 0 ? oa : blockIdx.y == 1 ? ob : oc;
  cast_body(src, dst);
}

__global__ void cast4(const float* __restrict__ a, const float* __restrict__ b,
                      const float* __restrict__ c, const float* __restrict__ d,
                      bf16_t* __restrict__ oa, bf16_t* __restrict__ ob,
                      bf16_t* __restrict__ oc, bf16_t* __restrict__ od) {
  const float* src = blockIdx.y == 0 ? a : blockIdx.y == 1 ? b
                   : blockIdx.y == 2 ? c : d;
  bf16_t* dst = blockIdx.y == 0 ? oa : blockIdx.y == 1 ? ob
              : blockIdx.y == 2 ? oc : od;
  cast_body(src, dst);
}

// ---------------------------------------------------------------- bt-GEMM
// C[m,n] = (sum_k A[m,k]*Bw[n,k] + bias[n]) * scale.  A: MxK bf16 rm, Bw: NxK bf16 rm.
// OUT_MODE 0: bf16 row-major MxN. 1: bf16 transposed to (B,NH,HD,S). 2: f32 MxN.
template <int M, int N, int K, int OUT_MODE>
__global__ __launch_bounds__(256, 2) void gemm_bt(const bf16_t* __restrict__ A,
                                                  const bf16_t* __restrict__ Bw,
                                                  const float* __restrict__ bias,
                                                  void* __restrict__ Cout,
                                                  float scale) {
  constexpr int BM = 128, BN = 128, BK = 64;
  __shared__ __align__(16) bf16_t As[BM * BK];
  __shared__ __align__(16) bf16_t Bs[BN * BK];
  const int tid = threadIdx.x;
  const int lane = tid & 63;
  const int wave = tid >> 6;
  const int bm = blockIdx.x & (M / BM - 1);
  const int bn = blockIdx.x / (M / BM);
  const int wm = wave >> 1, wn = wave & 1;
  const int quad = lane >> 4, l15 = lane & 15;

  int s_r[4], s_c[4];
#pragma unroll
  for (int i = 0; i < 4; ++i) {
    int seg = wave * 4 + i;
    int r = seg * 8 + (lane >> 3);
    s_r[i] = r;
    s_c[i] = (lane & 7) ^ (r & 7);
  }
  const bf16_t* Abase = A + (size_t)bm * BM * K;
  const bf16_t* Bbase = Bw + (size_t)bn * BN * K;

  f32x4 zero4 = {0.f, 0.f, 0.f, 0.f};
  f32x4 acc[4][4];
#pragma unroll
  for (int i = 0; i < 4; ++i)
#pragma unroll
    for (int j = 0; j < 4; ++j) acc[i][j] = zero4;

  int arow[4], brow[4];
#pragma unroll
  for (int t = 0; t < 4; ++t) {
    arow[t] = wm * 64 + t * 16 + l15;
    brow[t] = wn * 64 + t * 16 + l15;
  }

  for (int kt = 0; kt < K / BK; ++kt) {
    const int k0 = kt * BK;
#pragma unroll
    for (int i = 0; i < 4; ++i) {
      int seg = wave * 4 + i;
      async_copy16(Abase + (size_t)s_r[i] * K + k0 + s_c[i] * 8, As + seg * 512);
      async_copy16(Bbase + (size_t)s_r[i] * K + k0 + s_c[i] * 8, Bs + seg * 512);
    }
    __syncthreads();
#pragma unroll
    for (int ks = 0; ks < 2; ++ks) {
      bf16x8 af[4], bfv[4];
#pragma unroll
      for (int mt = 0; mt < 4; ++mt)
        af[mt] = *(const bf16x8*)(As + arow[mt] * 64 +
                                  (((ks * 4 + quad) ^ (arow[mt] & 7)) * 8));
#pragma unroll
      for (int nt = 0; nt < 4; ++nt)
        bfv[nt] = *(const bf16x8*)(Bs + brow[nt] * 64 +
                                   (((ks * 4 + quad) ^ (brow[nt] & 7)) * 8));
#pragma unroll
      for (int mt = 0; mt < 4; ++mt)
#pragma unroll
        for (int nt = 0; nt < 4; ++nt)
          acc[mt][nt] = __builtin_amdgcn_mfma_f32_16x16x32_bf16(
              af[mt], bfv[nt], acc[mt][nt], 0, 0, 0);
    }
    __syncthreads();
  }

  float bv[4];
#pragma unroll
  for (int nt = 0; nt < 4; ++nt) bv[nt] = bias[bn * BN + brow[nt]];

#pragma unroll
  for (int mt = 0; mt < 4; ++mt) {
    const int rbase = bm * BM + wm * 64 + mt * 16 + quad * 4;
#pragma unroll
    for (int nt = 0; nt < 4; ++nt) {
      const int col = bn * BN + brow[nt];
      if constexpr (OUT_MODE == 0) {
        bf16_t* C = (bf16_t*)Cout;
#pragma unroll
        for (int r = 0; r < 4; ++r)
          C[(size_t)(rbase + r) * N + col] = (bf16_t)((acc[mt][nt][r] + bv[nt]) * scale);
      } else if constexpr (OUT_MODE == 2) {
        float* C = (float*)Cout;
#pragma unroll
        for (int r = 0; r < 4; ++r)
          C[(size_t)(rbase + r) * N + col] = acc[mt][nt][r] + bv[nt];
      } else {  // transposed bf16 -> (B, NH, HD, S)
        bf16_t* C = (bf16_t*)Cout;
        const int bb = rbase >> 11;
        const int s0 = rbase & (Sc - 1);
        const int h = col >> 7, d = col & (HDc - 1);
        union { bf16_t h4[4]; uint2 u; } o;
#pragma unroll
        for (int r = 0; r < 4; ++r) o.h4[r] = (bf16_t)(acc[mt][nt][r] + bv[nt]);
        *(uint2*)(C + (((size_t)(bb * NHc + h) * HDc + d) * Sc + s0)) = o.u;
      }
    }
  }
}

// ---------------------------------------------------------------- flash attention
// ROUND-1 GEOMETRY (known good): grid = B*NH*(S/128) = 512; block = 256 (4 waves).
// Wave w owns q-rows [32w,32w+32). KV tiles of 128 keys.
// LDS: K 32KB | Vt 32KB | P bf16 per-wave 32 x PSTR -> 65536 + 4*8704 = 100352 B.
// Q is pre-scaled by 1/sqrt(HD) in the q-projection.
__global__ __launch_bounds__(256, 1) void flash_attn(const bf16_t* __restrict__ Q,
                                                     const bf16_t* __restrict__ Kg,
                                                     const bf16_t* __restrict__ Vt,
                                                     bf16_t* __restrict__ ctx) {
  extern __shared__ char smem[];
  bf16_t* Ks = (bf16_t*)smem;              // 128 keys x 128 hd
  bf16_t* Vs = (bf16_t*)(smem + 32768);    // 128 hd x 128 keys (transposed V)
  bf16_t* Ps = (bf16_t*)(smem + 65536);    // per-wave 32 x PSTR bf16

  const int tid = threadIdx.x, lane = tid & 63, wave = tid >> 6;
  const int quad = lane >> 4, l15 = lane & 15;
  const int bid = blockIdx.x;
  const int qt = bid & 15, h = (bid >> 4) & 15, b = bid >> 8;

  bf16_t* Pw = Ps + wave * (32 * PSTR);

  // Q fragments, held in registers for all 16 kv-tiles
  bf16x8 qf[2][4];
#pragma unroll
  for (int mt = 0; mt < 2; ++mt) {
    int grow = b * Sc + qt * 128 + wave * 32 + mt * 16 + l15;
    const bf16_t* qp = Q + (size_t)grow * Hc + h * HDc;
#pragma unroll
    for (int kc = 0; kc < 4; ++kc) qf[mt][kc] = *(const bf16x8*)(qp + kc * 32 + quad * 8);
  }

  f32x4 zero4 = {0.f, 0.f, 0.f, 0.f};
  f32x4 o[2][8];
#pragma unroll
  for (int mt = 0; mt < 2; ++mt)
#pragma unroll
    for (int dt = 0; dt < 8; ++dt) o[mt][dt] = zero4;
  float mrow[2][4], lrow[2][4];
#pragma unroll
  for (int mt = 0; mt < 2; ++mt)
#pragma unroll
    for (int r = 0; r < 4; ++r) { mrow[mt][r] = -1e30f; lrow[mt][r] = 0.f; }

  // staging geometry (K tile: 32 segs of 1024B = 4 rows x 256B; wave owns 8 segs)
  int st_r[8], st_c[8];
#pragma unroll
  for (int i = 0; i < 8; ++i) {
    int seg = wave * 8 + i;
    st_r[i] = seg * 4 + (lane >> 4);
    st_c[i] = (lane & 15) ^ (st_r[i] & 7);
  }
  const bf16_t* Kbase = Kg + (size_t)b * Sc * Hc + h * HDc;
  const bf16_t* Vbase = Vt + (size_t)(b * NHc + h) * HDc * Sc;

  for (int kb = 0; kb < 16; ++kb) {
#pragma unroll
    for (int i = 0; i < 8; ++i) {
      int seg = wave * 8 + i;
      async_copy16(Kbase + (size_t)(kb * 128 + st_r[i]) * Hc + st_c[i] * 8, Ks + seg * 512);
      async_copy16(Vbase + (size_t)st_r[i] * Sc + kb * 128 + st_c[i] * 8, Vs + seg * 512);
    }
    __syncthreads();

    // S = Q K^T  (kc outer -> 16 independent MFMA chains)
    f32x4 sf[2][8];
#pragma unroll
    for (int mt = 0; mt < 2; ++mt)
#pragma unroll
      for (int nt = 0; nt < 8; ++nt) sf[mt][nt] = zero4;
#pragma unroll
    for (int kc = 0; kc < 4; ++kc)
#pragma unroll
      for (int nt = 0; nt < 8; ++nt) {
        int kr = nt * 16 + l15;
        bf16x8 kf = *(const bf16x8*)(Ks + kr * 128 + (((kc * 4 + quad) ^ (kr & 7)) * 8));
        sf[0][nt] = __builtin_amdgcn_mfma_f32_16x16x32_bf16(qf[0][kc], kf, sf[0][nt], 0, 0, 0);
        sf[1][nt] = __builtin_amdgcn_mfma_f32_16x16x32_bf16(qf[1][kc], kf, sf[1][nt], 0, 0, 0);
      }

    // online softmax (scores pre-scaled via Q; raw exp)
#pragma unroll
    for (int mt = 0; mt < 2; ++mt)
#pragma unroll
      for (int r = 0; r < 4; ++r) {
        float mx = sf[mt][0][r];
#pragma unroll
        for (int nt = 1; nt < 8; ++nt) mx = fmaxf(mx, sf[mt][nt][r]);
#pragma unroll
        for (int off = 1; off < 16; off <<= 1) mx = fmaxf(mx, __shfl_xor(mx, off));
        float mnew = fmaxf(mrow[mt][r], mx);
        float alpha = __expf(mrow[mt][r] - mnew);
        float rs = 0.f;
#pragma unroll
        for (int nt = 0; nt < 8; ++nt) {
          float p = __expf(sf[mt][nt][r] - mnew);
          sf[mt][nt][r] = p;
          rs += p;
        }
#pragma unroll
        for (int off = 1; off < 16; off <<= 1) rs += __shfl_xor(rs, off);
        lrow[mt][r] = lrow[mt][r] * alpha + rs;
        mrow[mt][r] = mnew;
#pragma unroll
        for (int dt = 0; dt < 8; ++dt) o[mt][dt][r] *= alpha;
      }

    // P: C-layout regs -> LDS bf16 (stride PSTR, rows 16B-aligned)
    //    -> A-layout bf16x8 frags (wave-private region, no barrier)
#pragma unroll
    for (int mt = 0; mt < 2; ++mt)
#pragma unroll
      for (int nt = 0; nt < 8; ++nt)
#pragma unroll
        for (int r = 0; r < 4; ++r)
          Pw[(mt * 16 + quad * 4 + r) * PSTR + nt * 16 + l15] = (bf16_t)sf[mt][nt][r];

    bf16x8 pf[2][4];
#pragma unroll
    for (int mt = 0; mt < 2; ++mt) {
      const bf16_t* pr = Pw + (mt * 16 + l15) * PSTR;
#pragma unroll
      for (int kc = 0; kc < 4; ++kc)
        pf[mt][kc] = *(const bf16x8*)(pr + kc * 32 + quad * 8);
    }

    // O += P V
#pragma unroll
    for (int kc = 0; kc < 4; ++kc)
#pragma unroll
      for (int dt = 0; dt < 8; ++dt) {
        int vr = dt * 16 + l15;
        bf16x8 vf = *(const bf16x8*)(Vs + vr * 128 + (((kc * 4 + quad) ^ (vr & 7)) * 8));
        o[0][dt] = __builtin_amdgcn_mfma_f32_16x16x32_bf16(pf[0][kc], vf, o[0][dt], 0, 0, 0);
        o[1][dt] = __builtin_amdgcn_mfma_f32_16x16x32_bf16(pf[1][kc], vf, o[1][dt], 0, 0, 0);
      }
    __syncthreads();
  }

  // epilogue: O/l -> LDS bf16 (reuse Pw) -> coalesced stores
#pragma unroll
  for (int mt = 0; mt < 2; ++mt) {
    float rinv[4];
#pragma unroll
    for (int r = 0; r < 4; ++r) rinv[r] = 1.f / lrow[mt][r];
#pragma unroll
    for (int dt = 0; dt < 8; ++dt)
#pragma unroll
      for (int r = 0; r < 4; ++r)
        Pw[(mt * 16 + quad * 4 + r) * PSTR + dt * 16 + l15] = (bf16_t)(o[mt][dt][r] * rinv[r]);
  }
#pragma unroll
  for (int r = 0; r < 32; ++r) {
    unsigned v = *(const unsigned*)(Pw + r * PSTR + lane * 2);
    int grow = b * Sc + qt * 128 + wave * 32 + r;
    *(unsigned*)(ctx + (size_t)grow * Hc + h * HDc + lane * 2) = v;
  }
}

// ---------------------------------------------------------------- launch
extern "C" void kernel_launch(void* const* d_in, const int* in_sizes, int n_in,
                              void* d_out, int out_size, void* d_ws, size_t ws_size,
                              hipStream_t stream) {
  const float* query = (const float*)d_in[0];
  const float* key_i = (const float*)d_in[1];
  const float* value = (const float*)d_in[2];
  const float* Wq = (const float*)d_in[3];
  const float* bq = (const float*)d_in[4];
  const float* Wk = (const float*)d_in[5];
  const float* bk = (const float*)d_in[6];
  const float* Wv = (const float*)d_in[7];
  const float* bv = (const float*)d_in[8];
  const float* Wo = (const float*)d_in[9];
  const float* bo = (const float*)d_in[10];

  const size_t XE = (size_t)Bc * Sc * Hc;  // 8,388,608
  const size_t WE = (size_t)Hc * Hc;       // 4,194,304
  const size_t need = 6 * XE * 2 + 4 * WE * 2;  // 128 MB
  if (ws_size < need) return;

  char* ws = (char*)d_ws;
  size_t off = 0;
  auto alloc = [&](size_t bytes) {
    char* p = ws + off;
    off += (bytes + 255) & ~(size_t)255;
    return p;
  };
  bf16_t* Xq = (bf16_t*)alloc(XE * 2);
  bf16_t* Xk = (bf16_t*)alloc(XE * 2);
  bf16_t* Xv = (bf16_t*)alloc(XE * 2);
  bf16_t* Wqb = (bf16_t*)alloc(WE * 2);
  bf16_t* Wkb = (bf16_t*)alloc(WE * 2);
  bf16_t* Wvb = (bf16_t*)alloc(WE * 2);
  bf16_t* Wob = (bf16_t*)alloc(WE * 2);
  bf16_t* qb = (bf16_t*)alloc(XE * 2);
  bf16_t* kb = (bf16_t*)alloc(XE * 2);
  bf16_t* vtb = (bf16_t*)alloc(XE * 2);
  bf16_t* ctxb = Xq;  // Xq dead after q-projection; reuse for ctx

  cast3<<<dim3((unsigned)(XE / 2048), 3), 256, 0, stream>>>(query, key_i, value, Xq, Xk, Xv);
  cast4<<<dim3((unsigned)(WE / 2048), 4), 256, 0, stream>>>(Wq, Wk, Wv, Wo, Wqb, Wkb, Wvb, Wob);

  gemm_bt<4096, 2048, 2048, 0><<<512, 256, 0, stream>>>(Xq, Wqb, bq, qb, SCALE_F);
  gemm_bt<4096, 2048, 2048, 0><<<512, 256, 0, stream>>>(Xk, Wkb, bk, kb, 1.0f);
  gemm_bt<4096, 2048, 2048, 1><<<512, 256, 0, stream>>>(Xv, Wvb, bv, vtb, 1.0f);

  hipFuncSetAttribute((const void*)flash_attn,
                      hipFuncAttributeMaxDynamicSharedMemorySize, 100352);
  flash_attn<<<512, 256, 100352, stream>>>(qb, kb, vtb, ctxb);

  gemm_bt<4096, 2048, 2048, 2><<<512, 256, 0, stream>>>(ctxb, Wob, bo, (float*)d_out, 1.0f);
}

// Round 5
// 477.841 us; speedup vs baseline: 1.0687x; 1.0511x over previous
//
#include <hip/hip_runtime.h>

// MultiHeadAttention MI355X (gfx950)
// B=2, S=2048, H=2048, NH=16, HD=128. fp32 in/out, bf16 MFMA compute.
// Pipeline: cast -> 3x proj GEMM (V transposed out, Q pre-scaled) -> flash attention -> out GEMM.
// R5: flash uses 64-key KV tiles so LDS=51200B -> 2 blocks/CU (2 waves/SIMD co-scheduling).

typedef __bf16 bf16_t;
typedef __bf16 bf16x8 __attribute__((ext_vector_type(8)));
typedef float  f32x4  __attribute__((ext_vector_type(4)));

#define DEVI __device__ __forceinline__

DEVI void async_copy16(const void* gsrc, void* ldst) {
  __builtin_amdgcn_global_load_lds(
      (const __attribute__((address_space(1))) unsigned int*)gsrc,
      (__attribute__((address_space(3))) unsigned int*)ldst, 16, 0, 0);
}

constexpr int Bc = 2, Sc = 2048, Hc = 2048, NHc = 16, HDc = 128;
constexpr float SCALE_F = 0.088388347648318447f;  // 1/sqrt(128)
constexpr int PSTR = 72;  // P row stride (bf16): 72*2=144B=9*16 -> rows 16B-aligned

// ---------------------------------------------------------------- casts (merged launches)
DEVI void cast_body(const float* __restrict__ in, bf16_t* __restrict__ out) {
  int i = (blockIdx.x * 256 + threadIdx.x) * 8;
  float4 f0 = *(const float4*)(in + i);
  float4 f1 = *(const float4*)(in + i + 4);
  union { bf16_t h[8]; uint4 u; } o;
  o.h[0] = (bf16_t)f0.x; o.h[1] = (bf16_t)f0.y;
  o.h[2] = (bf16_t)f0.z; o.h[3] = (bf16_t)f0.w;
  o.h[4] = (bf16_t)f1.x; o.h[5] = (bf16_t)f1.y;
  o.h[6] = (bf16_t)f1.z; o.h[7] = (bf16_t)f1.w;
  *(uint4*)(out + i) = o.u;
}

__global__ void cast3(const float* __restrict__ a, const float* __restrict__ b,
                      const float* __restrict__ c, bf16_t* __restrict__ oa,
                      bf16_t* __restrict__ ob, bf16_t* __restrict__ oc) {
  const float* src = blockIdx.y == 0 ? a : blockIdx.y == 1 ? b : c;
  bf16_t* dst = blockIdx.y == 0 ? oa : blockIdx.y == 1 ? ob : oc;
  cast_body(src, dst);
}

__global__ void cast4(const float* __restrict__ a, const float* __restrict__ b,
                      const float* __restrict__ c, const float* __restrict__ d,
                      bf16_t* __restrict__ oa, bf16_t* __restrict__ ob,
                      bf16_t* __restrict__ oc, bf16_t* __restrict__ od) {
  const float* src = blockIdx.y == 0 ? a : blockIdx.y == 1 ? b
                   : blockIdx.y == 2 ? c : d;
  bf16_t* dst = blockIdx.y == 0 ? oa : blockIdx.y == 1 ? ob
              : blockIdx.y == 2 ? oc : od;
  cast_body(src, dst);
}

// ---------------------------------------------------------------- bt-GEMM
// C[m,n] = (sum_k A[m,k]*Bw[n,k] + bias[n]) * scale.  A: MxK bf16 rm, Bw: NxK bf16 rm.
// OUT_MODE 0: bf16 row-major MxN. 1: bf16 transposed to (B,NH,HD,S). 2: f32 MxN.
template <int M, int N, int K, int OUT_MODE>
__global__ __launch_bounds__(256, 2) void gemm_bt(const bf16_t* __restrict__ A,
                                                  const bf16_t* __restrict__ Bw,
                                                  const float* __restrict__ bias,
                                                  void* __restrict__ Cout,
                                                  float scale) {
  constexpr int BM = 128, BN = 128, BK = 64;
  __shared__ __align__(16) bf16_t As[BM * BK];
  __shared__ __align__(16) bf16_t Bs[BN * BK];
  const int tid = threadIdx.x;
  const int lane = tid & 63;
  const int wave = tid >> 6;
  const int bm = blockIdx.x & (M / BM - 1);
  const int bn = blockIdx.x / (M / BM);
  const int wm = wave >> 1, wn = wave & 1;
  const int quad = lane >> 4, l15 = lane & 15;

  int s_r[4], s_c[4];
#pragma unroll
  for (int i = 0; i < 4; ++i) {
    int seg = wave * 4 + i;
    int r = seg * 8 + (lane >> 3);
    s_r[i] = r;
    s_c[i] = (lane & 7) ^ (r & 7);
  }
  const bf16_t* Abase = A + (size_t)bm * BM * K;
  const bf16_t* Bbase = Bw + (size_t)bn * BN * K;

  f32x4 zero4 = {0.f, 0.f, 0.f, 0.f};
  f32x4 acc[4][4];
#pragma unroll
  for (int i = 0; i < 4; ++i)
#pragma unroll
    for (int j = 0; j < 4; ++j) acc[i][j] = zero4;

  int arow[4], brow[4];
#pragma unroll
  for (int t = 0; t < 4; ++t) {
    arow[t] = wm * 64 + t * 16 + l15;
    brow[t] = wn * 64 + t * 16 + l15;
  }

  for (int kt = 0; kt < K / BK; ++kt) {
    const int k0 = kt * BK;
#pragma unroll
    for (int i = 0; i < 4; ++i) {
      int seg = wave * 4 + i;
      async_copy16(Abase + (size_t)s_r[i] * K + k0 + s_c[i] * 8, As + seg * 512);
      async_copy16(Bbase + (size_t)s_r[i] * K + k0 + s_c[i] * 8, Bs + seg * 512);
    }
    __syncthreads();
#pragma unroll
    for (int ks = 0; ks < 2; ++ks) {
      bf16x8 af[4], bfv[4];
#pragma unroll
      for (int mt = 0; mt < 4; ++mt)
        af[mt] = *(const bf16x8*)(As + arow[mt] * 64 +
                                  (((ks * 4 + quad) ^ (arow[mt] & 7)) * 8));
#pragma unroll
      for (int nt = 0; nt < 4; ++nt)
        bfv[nt] = *(const bf16x8*)(Bs + brow[nt] * 64 +
                                   (((ks * 4 + quad) ^ (brow[nt] & 7)) * 8));
#pragma unroll
      for (int mt = 0; mt < 4; ++mt)
#pragma unroll
        for (int nt = 0; nt < 4; ++nt)
          acc[mt][nt] = __builtin_amdgcn_mfma_f32_16x16x32_bf16(
              af[mt], bfv[nt], acc[mt][nt], 0, 0, 0);
    }
    __syncthreads();
  }

  float bv[4];
#pragma unroll
  for (int nt = 0; nt < 4; ++nt) bv[nt] = bias[bn * BN + brow[nt]];

#pragma unroll
  for (int mt = 0; mt < 4; ++mt) {
    const int rbase = bm * BM + wm * 64 + mt * 16 + quad * 4;
#pragma unroll
    for (int nt = 0; nt < 4; ++nt) {
      const int col = bn * BN + brow[nt];
      if constexpr (OUT_MODE == 0) {
        bf16_t* C = (bf16_t*)Cout;
#pragma unroll
        for (int r = 0; r < 4; ++r)
          C[(size_t)(rbase + r) * N + col] = (bf16_t)((acc[mt][nt][r] + bv[nt]) * scale);
      } else if constexpr (OUT_MODE == 2) {
        float* C = (float*)Cout;
#pragma unroll
        for (int r = 0; r < 4; ++r)
          C[(size_t)(rbase + r) * N + col] = acc[mt][nt][r] + bv[nt];
      } else {  // transposed bf16 -> (B, NH, HD, S)
        bf16_t* C = (bf16_t*)Cout;
        const int bb = rbase >> 11;
        const int s0 = rbase & (Sc - 1);
        const int h = col >> 7, d = col & (HDc - 1);
        union { bf16_t h4[4]; uint2 u; } o;
#pragma unroll
        for (int r = 0; r < 4; ++r) o.h4[r] = (bf16_t)(acc[mt][nt][r] + bv[nt]);
        *(uint2*)(C + (((size_t)(bb * NHc + h) * HDc + d) * Sc + s0)) = o.u;
      }
    }
  }
}

// ---------------------------------------------------------------- flash attention
// grid = B*NH*(S/128) = 512; block = 256 (4 waves); 2 blocks/CU (2 waves/SIMD).
// KV tiles of 64 keys -> 32 iterations. Wave w owns q-rows [32w,32w+32).
// LDS (static, 51200 B): K 64x128 (16K) | Vt 128x64 (16K) | P 4 x 32 x PSTR (18K).
// Epilogue O overlays Ks/Vs (one post-loop barrier). Q pre-scaled by 1/sqrt(HD).
__global__ __launch_bounds__(256, 2) void flash_attn(const bf16_t* __restrict__ Q,
                                                     const bf16_t* __restrict__ Kg,
                                                     const bf16_t* __restrict__ Vt,
                                                     bf16_t* __restrict__ ctx) {
  __shared__ __align__(16) bf16_t smem[64 * 128 + 128 * 64 + 4 * 32 * PSTR];
  bf16_t* Ks = smem;            // 64 keys x 128 hd
  bf16_t* Vs = smem + 8192;     // 128 hd x 64 keys (transposed V)
  bf16_t* Ps = smem + 16384;    // per-wave 32 x PSTR

  const int tid = threadIdx.x, lane = tid & 63, wave = tid >> 6;
  const int quad = lane >> 4, l15 = lane & 15;
  const int bid = blockIdx.x;
  const int qt = bid & 15, h = (bid >> 4) & 15, b = bid >> 8;

  bf16_t* Pw = Ps + wave * (32 * PSTR);

  // Q fragments, held in registers for all 32 kv-tiles
  bf16x8 qf[2][4];
#pragma unroll
  for (int mt = 0; mt < 2; ++mt) {
    int grow = b * Sc + qt * 128 + wave * 32 + mt * 16 + l15;
    const bf16_t* qp = Q + (size_t)grow * Hc + h * HDc;
#pragma unroll
    for (int kc = 0; kc < 4; ++kc) qf[mt][kc] = *(const bf16x8*)(qp + kc * 32 + quad * 8);
  }

  f32x4 zero4 = {0.f, 0.f, 0.f, 0.f};
  f32x4 o[2][8];
#pragma unroll
  for (int mt = 0; mt < 2; ++mt)
#pragma unroll
    for (int dt = 0; dt < 8; ++dt) o[mt][dt] = zero4;
  float mrow[2][4], lrow[2][4];
#pragma unroll
  for (int mt = 0; mt < 2; ++mt)
#pragma unroll
    for (int r = 0; r < 4; ++r) { mrow[mt][r] = -1e30f; lrow[mt][r] = 0.f; }

  // staging: K tile = 16 segs of 1KB (4 rows x 256B); V tile = 16 segs (8 rows x 128B).
  // wave owns segs [4w,4w+4) of each.
  int kr_[4], kc_[4], vr_[4], vc_[4];
#pragma unroll
  for (int i = 0; i < 4; ++i) {
    int s = wave * 4 + i;
    kr_[i] = s * 4 + quad;        kc_[i] = l15 ^ (kr_[i] & 7);
    vr_[i] = s * 8 + (lane >> 3); vc_[i] = (lane & 7) ^ (vr_[i] & 7);
  }
  const bf16_t* Kbase = Kg + (size_t)b * Sc * Hc + h * HDc;
  const bf16_t* Vbase = Vt + (size_t)(b * NHc + h) * HDc * Sc;

  for (int kb = 0; kb < 32; ++kb) {
#pragma unroll
    for (int i = 0; i < 4; ++i) {
      int s = wave * 4 + i;
      async_copy16(Kbase + (size_t)(kb * 64 + kr_[i]) * Hc + kc_[i] * 8, Ks + s * 512);
      async_copy16(Vbase + (size_t)vr_[i] * Sc + kb * 64 + vc_[i] * 8, Vs + s * 512);
    }
    __syncthreads();

    // S = Q K^T  (kc outer -> 8 independent MFMA chains)
    f32x4 sf[2][4];
#pragma unroll
    for (int mt = 0; mt < 2; ++mt)
#pragma unroll
      for (int nt = 0; nt < 4; ++nt) sf[mt][nt] = zero4;
#pragma unroll
    for (int kc = 0; kc < 4; ++kc)
#pragma unroll
      for (int nt = 0; nt < 4; ++nt) {
        int kr = nt * 16 + l15;
        bf16x8 kf = *(const bf16x8*)(Ks + kr * 128 + (((kc * 4 + quad) ^ (kr & 7)) * 8));
        sf[0][nt] = __builtin_amdgcn_mfma_f32_16x16x32_bf16(qf[0][kc], kf, sf[0][nt], 0, 0, 0);
        sf[1][nt] = __builtin_amdgcn_mfma_f32_16x16x32_bf16(qf[1][kc], kf, sf[1][nt], 0, 0, 0);
      }

    // online softmax (scores pre-scaled via Q; raw exp)
#pragma unroll
    for (int mt = 0; mt < 2; ++mt)
#pragma unroll
      for (int r = 0; r < 4; ++r) {
        float mx = sf[mt][0][r];
#pragma unroll
        for (int nt = 1; nt < 4; ++nt) mx = fmaxf(mx, sf[mt][nt][r]);
#pragma unroll
        for (int off = 1; off < 16; off <<= 1) mx = fmaxf(mx, __shfl_xor(mx, off));
        float mnew = fmaxf(mrow[mt][r], mx);
        float alpha = __expf(mrow[mt][r] - mnew);
        float rs = 0.f;
#pragma unroll
        for (int nt = 0; nt < 4; ++nt) {
          float p = __expf(sf[mt][nt][r] - mnew);
          sf[mt][nt][r] = p;
          rs += p;
        }
#pragma unroll
        for (int off = 1; off < 16; off <<= 1) rs += __shfl_xor(rs, off);
        lrow[mt][r] = lrow[mt][r] * alpha + rs;
        mrow[mt][r] = mnew;
#pragma unroll
        for (int dt = 0; dt < 8; ++dt) o[mt][dt][r] *= alpha;
      }

    // P: C-layout regs -> LDS bf16 (wave-private, rows 16B-aligned) -> A-layout frags
#pragma unroll
    for (int mt = 0; mt < 2; ++mt)
#pragma unroll
      for (int nt = 0; nt < 4; ++nt)
#pragma unroll
        for (int r = 0; r < 4; ++r)
          Pw[(mt * 16 + quad * 4 + r) * PSTR + nt * 16 + l15] = (bf16_t)sf[mt][nt][r];

    bf16x8 pf[2][2];
#pragma unroll
    for (int mt = 0; mt < 2; ++mt) {
      const bf16_t* pr = Pw + (mt * 16 + l15) * PSTR;
#pragma unroll
      for (int kc = 0; kc < 2; ++kc)
        pf[mt][kc] = *(const bf16x8*)(pr + kc * 32 + quad * 8);
    }

    // O += P V
#pragma unroll
    for (int kc = 0; kc < 2; ++kc)
#pragma unroll
      for (int dt = 0; dt < 8; ++dt) {
        int vr = dt * 16 + l15;
        bf16x8 vf = *(const bf16x8*)(Vs + vr * 64 + (((kc * 4 + quad) ^ (vr & 7)) * 8));
        o[0][dt] = __builtin_amdgcn_mfma_f32_16x16x32_bf16(pf[0][kc], vf, o[0][dt], 0, 0, 0);
        o[1][dt] = __builtin_amdgcn_mfma_f32_16x16x32_bf16(pf[1][kc], vf, o[1][dt], 0, 0, 0);
      }
    __syncthreads();
  }

  // epilogue: O/l -> Ks/Vs overlay (wave-private 32x128) -> coalesced stores
  __syncthreads();  // everyone done with Ks/Vs before overlay
  bf16_t* Ow = smem + wave * 4096;  // 32 rows x 128 cols
#pragma unroll
  for (int mt = 0; mt < 2; ++mt) {
    float rinv[4];
#pragma unroll
    for (int r = 0; r < 4; ++r) rinv[r] = 1.f / lrow[mt][r];
#pragma unroll
    for (int dt = 0; dt < 8; ++dt)
#pragma unroll
      for (int r = 0; r < 4; ++r)
        Ow[(mt * 16 + quad * 4 + r) * 128 + dt * 16 + l15] = (bf16_t)(o[mt][dt][r] * rinv[r]);
  }
#pragma unroll
  for (int r = 0; r < 32; ++r) {
    unsigned v = *(const unsigned*)(Ow + r * 128 + lane * 2);
    int grow = b * Sc + qt * 128 + wave * 32 + r;
    *(unsigned*)(ctx + (size_t)grow * Hc + h * HDc + lane * 2) = v;
  }
}

// ---------------------------------------------------------------- launch
extern "C" void kernel_launch(void* const* d_in, const int* in_sizes, int n_in,
                              void* d_out, int out_size, void* d_ws, size_t ws_size,
                              hipStream_t stream) {
  const float* query = (const float*)d_in[0];
  const float* key_i = (const float*)d_in[1];
  const float* value = (const float*)d_in[2];
  const float* Wq = (const float*)d_in[3];
  const float* bq = (const float*)d_in[4];
  const float* Wk = (const float*)d_in[5];
  const float* bk = (const float*)d_in[6];
  const float* Wv = (const float*)d_in[7];
  const float* bv = (const float*)d_in[8];
  const float* Wo = (const float*)d_in[9];
  const float* bo = (const float*)d_in[10];

  const size_t XE = (size_t)Bc * Sc * Hc;  // 8,388,608
  const size_t WE = (size_t)Hc * Hc;       // 4,194,304
  const size_t need = 6 * XE * 2 + 4 * WE * 2;  // 128 MB
  if (ws_size < need) return;

  char* ws = (char*)d_ws;
  size_t off = 0;
  auto alloc = [&](size_t bytes) {
    char* p = ws + off;
    off += (bytes + 255) & ~(size_t)255;
    return p;
  };
  bf16_t* Xq = (bf16_t*)alloc(XE * 2);
  bf16_t* Xk = (bf16_t*)alloc(XE * 2);
  bf16_t* Xv = (bf16_t*)alloc(XE * 2);
  bf16_t* Wqb = (bf16_t*)alloc(WE * 2);
  bf16_t* Wkb = (bf16_t*)alloc(WE * 2);
  bf16_t* Wvb = (bf16_t*)alloc(WE * 2);
  bf16_t* Wob = (bf16_t*)alloc(WE * 2);
  bf16_t* qb = (bf16_t*)alloc(XE * 2);
  bf16_t* kb = (bf16_t*)alloc(XE * 2);
  bf16_t* vtb = (bf16_t*)alloc(XE * 2);
  bf16_t* ctxb = Xq;  // Xq dead after q-projection; reuse for ctx

  cast3<<<dim3((unsigned)(XE / 2048), 3), 256, 0, stream>>>(query, key_i, value, Xq, Xk, Xv);
  cast4<<<dim3((unsigned)(WE / 2048), 4), 256, 0, stream>>>(Wq, Wk, Wv, Wo, Wqb, Wkb, Wvb, Wob);

  gemm_bt<4096, 2048, 2048, 0><<<512, 256, 0, stream>>>(Xq, Wqb, bq, qb, SCALE_F);
  gemm_bt<4096, 2048, 2048, 0><<<512, 256, 0, stream>>>(Xk, Wkb, bk, kb, 1.0f);
  gemm_bt<4096, 2048, 2048, 1><<<512, 256, 0, stream>>>(Xv, Wvb, bv, vtb, 1.0f);

  flash_attn<<<512, 256, 0, stream>>>(qb, kb, vtb, ctxb);

  gemm_bt<4096, 2048, 2048, 2><<<512, 256, 0, stream>>>(ctxb, Wob, bo, (float*)d_out, 1.0f);
}